// Round 4
// baseline (445.749 us; speedup 1.0000x reference)
//
#include <hip/hip_runtime.h>
#include <stdint.h>

// Problem constants (fixed by reference)
#define NB 2048           // batch N
#define NI 256            // input dim I
#define NJ 256            // out dim J
#define GK 300            // grid size K
#define KPAD 320          // K padded to multiple of 32
#define KK_PER_I (2*KPAD) // cos/sin interleaved: 640 reduction elems per i
#define NKC (NI*KK_PER_I/32)  // 5120 chunk-columns of 32 kk
#define CH_PER_I 20       // 32-kk chunks per i
#define SPLITK 32
#define II_PER_S (NI / SPLITK)   // 8 i-values per split-k slice
#define BM 128

typedef __bf16 bf16x8 __attribute__((ext_vector_type(8)));
typedef __bf16 bf16x2 __attribute__((ext_vector_type(2)));
typedef float  f32x4  __attribute__((ext_vector_type(4)));
typedef float  f32x2  __attribute__((ext_vector_type(2)));

__device__ __forceinline__ void sincos2pi(float ang, float& c, float& s) {
  float r = ang * 0.15915494309189535f;   // 1/(2*pi)
  r = r - floorf(r);
  c = __builtin_amdgcn_cosf(r);
  s = __builtin_amdgcn_sinf(r);
}

__device__ __forceinline__ unsigned int pkbf(float c, float s) {
  bf16x2 p; p.x = (__bf16)c; p.y = (__bf16)s;
  return __builtin_bit_cast(unsigned int, p);
}

// Complex rotation on packed {c,s} state; shuffle/neg form foldable to
// v_pk_mul/v_pk_fma (VOP3P, 2xf32 per instr): 2 ops vs 4 scalar.
__device__ __forceinline__ f32x2 crot(f32x2 cs, f32x2 rr) {
  f32x2 t = cs * (f32x2){rr.x, rr.x};       // {c*cr, s*cr}
  f32x2 sw = {-cs.y, cs.x};                 // {-s, c}
  return sw * (f32x2){rr.y, rr.y} + t;      // {c*cr - s*sr, s*cr + c*sr}
}

// ---------------------------------------------------------------------------
// Pass 1: coeffs fp32 [2][J][I][300] -> bf16 workspace in MFMA frag order.
// Frag(kc, jt) = 1KB: byte = q*256 + n*16 + jj*2; kk = kc*32 + q*8 + jj;
// kk = i*640 + 2k + d; j = jt*16 + n; uint low bf16 = cos coeff, high = sin.
// Coalesced reads (along K) + LDS transpose (pad 17 -> 2-way alias, free)
// feeding the 1KB-contiguous-per-wave write phase.
// ---------------------------------------------------------------------------
__global__ __launch_bounds__(256) void convert_b(const float* __restrict__ coeffs,
                                                 unsigned int* __restrict__ bw) {
  __shared__ uint4 sb[80][17];            // [g][jr], +1 pad: 21.8 KB
  const int bid = blockIdx.x;
  const int i  = bid >> 4;
  const int jt = bid & 15;
  const int t  = (int)threadIdx.x;

  // Phase A: read along K, convert, stage to LDS.
  {
    const int jr = t >> 4;                // j within tile
    const int gq = t & 15;                // k-group: consecutive lanes -> consecutive float4
    const int j  = jt * 16 + jr;
    const float4* r0 = (const float4*)(coeffs + (size_t)(j * NI + i) * GK);
    const float4* r1 = (const float4*)(coeffs + (size_t)((NJ + j) * NI + i) * GK);
    #pragma unroll
    for (int p = 0; p < 5; p++) {
      const int g = p * 16 + gq;          // 0..79; >=75 is zero pad
      uint4 w = {0u, 0u, 0u, 0u};
      if (g < GK / 4) {
        float4 a = r0[g];
        float4 b = r1[g];
        w.x = pkbf(a.x, b.x);
        w.y = pkbf(a.y, b.y);
        w.z = pkbf(a.z, b.z);
        w.w = pkbf(a.w, b.w);
      }
      sb[g][jr] = w;
    }
  }
  __syncthreads();
  // Phase B: original mapping; each wave writes 1KB contiguous.
  {
    const int n  = t & 15;
    const int gl = t >> 4;
    #pragma unroll
    for (int p = 0; p < 5; p++) {
      const int g = p * 16 + gl;
      const int kc = i * 20 + (g >> 2);
      const unsigned int idx = ((unsigned int)(kc * 16 + jt) << 8) + ((g & 3) << 6) + (n << 2);
      *(uint4*)(bw + idx) = sb[g][n];
    }
  }
}

// ---------------------------------------------------------------------------
// Pass 2: out[n][j] = bias[j]
// ---------------------------------------------------------------------------
__global__ __launch_bounds__(256) void init_out(const float* __restrict__ bias,
                                                float* __restrict__ out) {
  const int tid = blockIdx.x * 256 + threadIdx.x;     // 131072 float4s
  float4 b = ((const float4*)bias)[tid & 63];
  ((float4*)out)[tid] = b;
}

// ---------------------------------------------------------------------------
// Pass 3: barrier-free GEMM. C[2048][256] += A * Bt, KK = 163840.
// NO LDS, NO __syncthreads. Each lane generates its own MFMA A-fragment via
// in-register rotation. B fragments streamed global->VGPR with a 1-chunk
// register double buffer. Block 128m x 256n, 4 waves, wave tile 64x128
// (acc[4][8]). Grid: 16 mt x 32 s = 512 blocks = 2/CU.
//
// v3: XCD swizzle (FETCH 338->42MB, r2-verified). v4 changes:
//  - crot() packed rotation (v_pk_fma candidate): ~96 -> ~65 VALU/chunk.
//  - B-load for chunk c+1 issued per-nn right before the MFMA quad that
//    consumes bcur[nn] (counted-vmcnt distance 8, spread VMEM issue).
//  - s_setprio(1) around each MFMA quad (independent-wave regime, m191).
//  - Epilogue atomics rotated by slice id: the 32 split-k slices add to the
//    same out lines; identical emission order = line-by-line lockstep
//    collisions. Rotating (mm,nn) start by s decorrelates the bursts.
// ---------------------------------------------------------------------------
__global__ __launch_bounds__(256, 2) void fkan_gemm(const float* __restrict__ x,
                                                    const uint4* __restrict__ bw4,
                                                    float* __restrict__ out) {
  const int bid  = blockIdx.x;
  const int virt = (bid & 7) * 64 + (bid >> 3);   // bijective: 512 = 8 XCD * 64
  const int mt = virt & 15;
  const int s  = virt >> 4;         // split-k slice (i range s*8 .. s*8+7)
  const int m0 = mt * BM;

  const int t    = (int)threadIdx.x;
  const int lane = t & 63;
  const int wave = t >> 6;
  const int wr = wave >> 1;         // m half (64 rows)
  const int wc = wave & 1;          // n half (128 cols)
  const int q  = lane >> 4;         // quad -> k sub-block
  const int ln = lane & 15;         // row (A) / col (B) within 16-tile

  f32x4 acc[4][8];
  #pragma unroll
  for (int mm = 0; mm < 4; mm++)
    #pragma unroll
    for (int nn = 0; nn < 8; nn++)
      acc[mm][nn] = (f32x4){0.f, 0.f, 0.f, 0.f};

  // B fragment pointer: frag(kc, jt=wc*8+nn) at uint4 index (kc*16+jt)*64+lane
  const uint4* bptr = bw4 + (size_t)(wc * 8) * 64 + lane;

  int kc = s * (NKC / SPLITK);      // s*160, contiguous through the slice
  uint4 bcur[8], bnxt[8];
  #pragma unroll
  for (int nn = 0; nn < 8; nn++) bcur[nn] = bptr[(size_t)kc * 1024 + nn * 64];

  f32x2 st[4], r1[4], rD[4];        // packed {c,s} state + rotators

  #pragma unroll 1
  for (int ii = 0; ii < II_PER_S; ii++) {
    const int i = s * II_PER_S + ii;
    // Per-i, per-m-tile trig seeds. Lane's A rows: m0 + wr*64 + mm*16 + ln.
    #pragma unroll
    for (int mm = 0; mm < 4; mm++) {
      const float xv = x[(m0 + wr * 64 + mm * 16 + ln) * NI + i];
      float c, sn;
      sincos2pi(xv, c, sn);          r1[mm] = (f32x2){c, sn};  // rotate-by-1
      sincos2pi(13.f * xv, c, sn);   rD[mm] = (f32x2){c, sn};  // rotate-by-13
      sincos2pi(xv * (float)(q * 4 + 1), c, sn);
      st[mm] = (f32x2){c, sn};                                 // state @ k=q*4+1
    }

    #pragma unroll 2
    for (int c = 0; c < CH_PER_I; c++) {
      const int kcn = (kc + 1 < NKC) ? kc + 1 : kc;   // clamp final prefetch

      // Generate A fragments in registers: lane holds A[m=ln][kk=q*8+jj],
      // jj=2t+d -> [cos,sin] pairs at k = 16*c + q*4 + {1,2,3,4}
      bf16x8 af[4];
      #pragma unroll
      for (int mm = 0; mm < 4; mm++) {
        f32x2 cs = st[mm];
        uint4 u;
        u.x = pkbf(cs.x, cs.y);
        cs = crot(cs, r1[mm]); u.y = pkbf(cs.x, cs.y);
        cs = crot(cs, r1[mm]); u.z = pkbf(cs.x, cs.y);
        cs = crot(cs, r1[mm]); u.w = pkbf(cs.x, cs.y);
        st[mm] = crot(cs, rD[mm]);
        af[mm] = __builtin_bit_cast(bf16x8, u);
      }

      // Per nn: issue next-chunk load, then the 4 MFMAs on current chunk.
      #pragma unroll
      for (int nn = 0; nn < 8; nn++) {
        bnxt[nn] = bptr[(size_t)kcn * 1024 + nn * 64];
        const bf16x8 bfr = __builtin_bit_cast(bf16x8, bcur[nn]);
        __builtin_amdgcn_s_setprio(1);
        #pragma unroll
        for (int mm = 0; mm < 4; mm++)
          acc[mm][nn] = __builtin_amdgcn_mfma_f32_16x16x32_bf16(
              af[mm], bfr, acc[mm][nn], 0, 0, 0);
        __builtin_amdgcn_s_setprio(0);
      }

      #pragma unroll
      for (int nn = 0; nn < 8; nn++) bcur[nn] = bnxt[nn];
      kc++;
    }
  }

  // ---- Epilogue: atomic accumulate (C/D layout: col=lane&15, row=q*4+r) ----
  // Rotated emission order: decorrelate the 32 slices' same-line bursts.
  const int r0 = m0 + wr * 64 + q * 4;
  const int c0 = wc * 128 + ln;
  const int nnrot = s & 7;
  const int mmrot = (s >> 3) & 3;
  #pragma unroll
  for (int mi = 0; mi < 4; mi++) {
    const int mm = (mi + mmrot) & 3;
    #pragma unroll
    for (int ni = 0; ni < 8; ni++) {
      const int nn = (ni + nnrot) & 7;
      #pragma unroll
      for (int r = 0; r < 4; r++)
        atomicAdd(&out[(r0 + mm * 16 + r) * NJ + c0 + nn * 16], acc[mm][nn][r]);
    }
  }
}

// ---------------------------------------------------------------------------
extern "C" void kernel_launch(void* const* d_in, const int* in_sizes, int n_in,
                              void* d_out, int out_size, void* d_ws, size_t ws_size,
                              hipStream_t stream) {
  const float* x      = (const float*)d_in[0];   // [2048, 256]
  const float* coeffs = (const float*)d_in[1];   // [2, 256, 256, 300]
  const float* bias   = (const float*)d_in[2];   // [1, 256]
  float* out = (float*)d_out;                    // [2048, 256] fp32
  unsigned int* bw = (unsigned int*)d_ws;        // 83.9 MB bf16 B in fragment order

  // Pass 1: B conversion (ws re-poisoned every call, so always rebuild)
  convert_b<<<dim3(NI * 16), dim3(256), 0, stream>>>(coeffs, bw);
  // Pass 2: out = bias
  init_out<<<dim3(NB * NJ / 4 / 256), dim3(256), 0, stream>>>(bias, out);
  // Pass 3: barrier-free GEMM with split-K atomics, XCD-swizzled
  fkan_gemm<<<dim3(16 * SPLITK), dim3(256), 0, stream>>>(x, (const uint4*)bw, out);
}

// Round 5
// 410.498 us; speedup vs baseline: 1.0859x; 1.0859x over previous
//
#include <hip/hip_runtime.h>
#include <stdint.h>

// Problem constants (fixed by reference)
#define NB 2048           // batch N
#define NI 256            // input dim I
#define NJ 256            // out dim J
#define GK 300            // grid size K
#define KPAD 320          // K padded to multiple of 32
#define KK_PER_I (2*KPAD) // cos/sin interleaved: 640 reduction elems per i
#define NKC (NI*KK_PER_I/32)  // 5120 chunk-columns of 32 kk
#define CH_PER_I 20       // 32-kk chunks per i
#define SPLITK 32
#define II_PER_S (NI / SPLITK)   // 8 i-values per split-k slice
#define BM 128

#define B_BYTES  ((size_t)NKC * 16 * 1024)          // 80 MiB fragment workspace
#define P_BYTES  ((size_t)SPLITK * NB * NJ * 4)     // 64 MiB partial tiles

typedef __bf16 bf16x8 __attribute__((ext_vector_type(8)));
typedef __bf16 bf16x2 __attribute__((ext_vector_type(2)));
typedef float  f32x4  __attribute__((ext_vector_type(4)));

__device__ __forceinline__ void sincos2pi(float ang, float& c, float& s) {
  float r = ang * 0.15915494309189535f;   // 1/(2*pi)
  r = r - floorf(r);
  c = __builtin_amdgcn_cosf(r);
  s = __builtin_amdgcn_sinf(r);
}

__device__ __forceinline__ unsigned int pkbf(float c, float s) {
  bf16x2 p; p.x = (__bf16)c; p.y = (__bf16)s;
  return __builtin_bit_cast(unsigned int, p);
}

__device__ __forceinline__ void rot(float& c, float& s, float cr, float sr) {
  float nc = c * cr - s * sr;
  s = s * cr + c * sr;
  c = nc;
}

// ---------------------------------------------------------------------------
// Pass 1: coeffs fp32 [2][J][I][300] -> bf16 workspace in MFMA frag order.
// Frag(kc, jt) = 1KB: byte = q*256 + n*16 + jj*2; kk = kc*32 + q*8 + jj;
// kk = i*640 + 2k + d; j = jt*16 + n; uint low bf16 = cos coeff, high = sin.
// Coalesced reads (along K) + LDS transpose (pad 17 -> 2-way alias, free)
// feeding the 1KB-contiguous-per-wave write phase.
// ---------------------------------------------------------------------------
__global__ __launch_bounds__(256) void convert_b(const float* __restrict__ coeffs,
                                                 unsigned int* __restrict__ bw) {
  __shared__ uint4 sb[80][17];            // [g][jr], +1 pad: 21.8 KB
  const int bid = blockIdx.x;
  const int i  = bid >> 4;
  const int jt = bid & 15;
  const int t  = (int)threadIdx.x;

  // Phase A: read along K, convert, stage to LDS.
  {
    const int jr = t >> 4;                // j within tile
    const int gq = t & 15;                // k-group: consecutive lanes -> consecutive float4
    const int j  = jt * 16 + jr;
    const float4* r0 = (const float4*)(coeffs + (size_t)(j * NI + i) * GK);
    const float4* r1 = (const float4*)(coeffs + (size_t)((NJ + j) * NI + i) * GK);
    #pragma unroll
    for (int p = 0; p < 5; p++) {
      const int g = p * 16 + gq;          // 0..79; >=75 is zero pad
      uint4 w = {0u, 0u, 0u, 0u};
      if (g < GK / 4) {
        float4 a = r0[g];
        float4 b = r1[g];
        w.x = pkbf(a.x, b.x);
        w.y = pkbf(a.y, b.y);
        w.z = pkbf(a.z, b.z);
        w.w = pkbf(a.w, b.w);
      }
      sb[g][jr] = w;
    }
  }
  __syncthreads();
  // Phase B: original mapping; each wave writes 1KB contiguous.
  {
    const int n  = t & 15;
    const int gl = t >> 4;
    #pragma unroll
    for (int p = 0; p < 5; p++) {
      const int g = p * 16 + gl;
      const int kc = i * 20 + (g >> 2);
      const unsigned int idx = ((unsigned int)(kc * 16 + jt) << 8) + ((g & 3) << 6) + (n << 2);
      *(uint4*)(bw + idx) = sb[g][n];
    }
  }
}

// ---------------------------------------------------------------------------
// Pass 2 (atomic fallback path only): out[n][j] = bias[j]
// ---------------------------------------------------------------------------
__global__ __launch_bounds__(256) void init_out(const float* __restrict__ bias,
                                                float* __restrict__ out) {
  const int tid = blockIdx.x * 256 + threadIdx.x;     // 131072 float4s
  float4 b = ((const float4*)bias)[tid & 63];
  ((float4*)out)[tid] = b;
}

// ---------------------------------------------------------------------------
// Pass 3: barrier-free GEMM. C[2048][256] += A * Bt, KK = 163840.
// NO LDS, NO __syncthreads. Each lane generates its own MFMA A-fragment via
// in-register rotation (3x rot-by-1 + 1x rot-by-13 per 32-kk chunk per mm).
// B fragments streamed global->VGPR with a 1-chunk register double buffer.
// Block 128m x 256n, 4 waves, wave tile 64x128 (acc[4][8]).
// Grid: 16 mt x 32 s = 512 blocks = 2/CU. XCD swizzle: slice's 2.6MB B
// stream pinned to one XCD L2 (r2-verified: FETCH 338->42MB).
//
// v5 epilogue modes (r4 diagnostic: WRITE_SIZE = 64MiB = exactly 16.8M
// atomics x 4B -> split-K atomicAdds write through to the memory fabric;
// the synchronized all-blocks-finish burst is a ~40-55us serialized RMW
// tail at 0% MfmaUtil):
//   MODE 0: atomicAdd into out (fallback, identical to r2's v3).
//   MODE 1: plain streaming stores into per-slice partial tile P[s][m][j];
//           reduce_out sums the 32 partials (no RMW serialization).
// ---------------------------------------------------------------------------
template <int MODE>
__global__ __launch_bounds__(256, 2) void fkan_gemm(const float* __restrict__ x,
                                                    const uint4* __restrict__ bw4,
                                                    float* __restrict__ dst) {
  const int bid  = blockIdx.x;
  const int virt = (bid & 7) * 64 + (bid >> 3);   // bijective: 512 = 8 XCD * 64
  const int mt = virt & 15;
  const int s  = virt >> 4;         // split-k slice (i range s*8 .. s*8+7)
  const int m0 = mt * BM;

  const int t    = (int)threadIdx.x;
  const int lane = t & 63;
  const int wave = t >> 6;
  const int wr = wave >> 1;         // m half (64 rows)
  const int wc = wave & 1;          // n half (128 cols)
  const int q  = lane >> 4;         // quad -> k sub-block
  const int ln = lane & 15;         // row (A) / col (B) within 16-tile

  f32x4 acc[4][8];
  #pragma unroll
  for (int mm = 0; mm < 4; mm++)
    #pragma unroll
    for (int nn = 0; nn < 8; nn++)
      acc[mm][nn] = (f32x4){0.f, 0.f, 0.f, 0.f};

  // B fragment pointer: frag(kc, jt=wc*8+nn) at uint4 index (kc*16+jt)*64+lane
  const uint4* bptr = bw4 + (size_t)(wc * 8) * 64 + lane;

  int kc = s * (NKC / SPLITK);      // s*160, contiguous through the slice
  uint4 bcur[8], bnxt[8];
  #pragma unroll
  for (int nn = 0; nn < 8; nn++) bcur[nn] = bptr[(size_t)kc * 1024 + nn * 64];

  float stc[4], sts[4], c1a[4], s1a[4], cDa[4], sDa[4];

  #pragma unroll 1
  for (int ii = 0; ii < II_PER_S; ii++) {
    const int i = s * II_PER_S + ii;
    // Per-i, per-m-tile trig seeds. Lane's A rows: m0 + wr*64 + mm*16 + ln.
    #pragma unroll
    for (int mm = 0; mm < 4; mm++) {
      const float xv = x[(m0 + wr * 64 + mm * 16 + ln) * NI + i];
      sincos2pi(xv, c1a[mm], s1a[mm]);          // rotate-by-1 step
      sincos2pi(13.f * xv, cDa[mm], sDa[mm]);   // rotate-by-13 (chunk advance)
      sincos2pi(xv * (float)(q * 4 + 1), stc[mm], sts[mm]);  // state @ k=q*4+1
    }

    #pragma unroll 2
    for (int c = 0; c < CH_PER_I; c++) {
      // Prefetch next chunk's B fragments (consumed next iteration)
      const int kcn = (kc + 1 < NKC) ? kc + 1 : kc;   // clamp final prefetch
      #pragma unroll
      for (int nn = 0; nn < 8; nn++)
        bnxt[nn] = bptr[(size_t)kcn * 1024 + nn * 64];

      // Generate A fragments in registers: lane holds A[m=ln][kk=q*8+jj],
      // jj=2t+d -> [cos,sin] pairs at k = 16*c + q*4 + {1,2,3,4}
      bf16x8 af[4];
      #pragma unroll
      for (int mm = 0; mm < 4; mm++) {
        float cc = stc[mm], ss = sts[mm];
        uint4 u;
        u.x = pkbf(cc, ss);
        rot(cc, ss, c1a[mm], s1a[mm]); u.y = pkbf(cc, ss);
        rot(cc, ss, c1a[mm], s1a[mm]); u.z = pkbf(cc, ss);
        rot(cc, ss, c1a[mm], s1a[mm]); u.w = pkbf(cc, ss);
        rot(cc, ss, cDa[mm], sDa[mm]); stc[mm] = cc; sts[mm] = ss;
        af[mm] = __builtin_bit_cast(bf16x8, u);
      }

      // 32 MFMAs on the previously-loaded chunk
      #pragma unroll
      for (int nn = 0; nn < 8; nn++) {
        const bf16x8 bfr = __builtin_bit_cast(bf16x8, bcur[nn]);
        #pragma unroll
        for (int mm = 0; mm < 4; mm++)
          acc[mm][nn] = __builtin_amdgcn_mfma_f32_16x16x32_bf16(
              af[mm], bfr, acc[mm][nn], 0, 0, 0);
      }

      #pragma unroll
      for (int nn = 0; nn < 8; nn++) bcur[nn] = bnxt[nn];
      kc++;
    }
  }

  // ---- Epilogue (C/D layout: col=lane&15, row=q*4+r) ----
  const int r0 = m0 + wr * 64 + q * 4;
  const int c0 = wc * 128 + ln;
  if (MODE == 0) {
    // Atomic accumulate into out
    #pragma unroll
    for (int mm = 0; mm < 4; mm++)
      #pragma unroll
      for (int nn = 0; nn < 8; nn++)
        #pragma unroll
        for (int r = 0; r < 4; r++)
          atomicAdd(&dst[(r0 + mm * 16 + r) * NJ + c0 + nn * 16], acc[mm][nn][r]);
  } else {
    // Streaming stores into partial tile P[s][2048][256]
    float* p = dst + (size_t)s * NB * NJ;
    #pragma unroll
    for (int mm = 0; mm < 4; mm++)
      #pragma unroll
      for (int nn = 0; nn < 8; nn++)
        #pragma unroll
        for (int r = 0; r < 4; r++)
          p[(r0 + mm * 16 + r) * NJ + c0 + nn * 16] = acc[mm][nn][r];
  }
}

// ---------------------------------------------------------------------------
// Pass 4 (partial path): out[m][j] = bias[j] + sum_s P[s][m][j]
// 64MB coalesced read (32 independent loads/thread), 2MB write. ~12us.
// ---------------------------------------------------------------------------
__global__ __launch_bounds__(256) void reduce_out(const float* __restrict__ P,
                                                  const float* __restrict__ bias,
                                                  float* __restrict__ out) {
  const int m = blockIdx.x;            // 0..2047
  const int j = (int)threadIdx.x;      // 0..255
  const size_t base = (size_t)m * NJ + j;
  float acc = bias[j];
  #pragma unroll
  for (int s = 0; s < SPLITK; s++)
    acc += P[(size_t)s * NB * NJ + base];
  out[base] = acc;
}

// ---------------------------------------------------------------------------
extern "C" void kernel_launch(void* const* d_in, const int* in_sizes, int n_in,
                              void* d_out, int out_size, void* d_ws, size_t ws_size,
                              hipStream_t stream) {
  const float* x      = (const float*)d_in[0];   // [2048, 256]
  const float* coeffs = (const float*)d_in[1];   // [2, 256, 256, 300]
  const float* bias   = (const float*)d_in[2];   // [1, 256]
  float* out = (float*)d_out;                    // [2048, 256] fp32
  unsigned int* bw = (unsigned int*)d_ws;        // 80 MiB bf16 B in fragment order

  // Pass 1: B conversion (ws re-poisoned every call, so always rebuild)
  convert_b<<<dim3(NI * 16), dim3(256), 0, stream>>>(coeffs, bw);

  if (ws_size >= B_BYTES + P_BYTES) {
    // Partial-tile path: streaming stores + reduction (no fabric RMW tail)
    float* P = (float*)((char*)d_ws + B_BYTES);
    fkan_gemm<1><<<dim3(16 * SPLITK), dim3(256), 0, stream>>>(x, (const uint4*)bw, P);
    reduce_out<<<dim3(NB), dim3(256), 0, stream>>>(P, bias, out);
  } else {
    // Fallback: split-K atomics (identical to r2 best)
    init_out<<<dim3(NB * NJ / 4 / 256), dim3(256), 0, stream>>>(bias, out);
    fkan_gemm<0><<<dim3(16 * SPLITK), dim3(256), 0, stream>>>(x, (const uint4*)bw, out);
  }
}